// Round 10
// baseline (4158.664 us; speedup 1.0000x reference)
//
#include <hip/hip_runtime.h>

typedef _Float16 f16;
typedef f16   f16x8 __attribute__((ext_vector_type(8)));
typedef float f32x4 __attribute__((ext_vector_type(4)));

#define T_LEN 512
#define BATCH 64
#define HID   512

__device__ __forceinline__ float sigm(float x) { return 1.0f / (1.0f + __expf(-x)); }
__device__ __forceinline__ float tanh_f(float x) {
  x = fminf(fmaxf(x, -15.0f), 15.0f);
  float e = __expf(2.0f * x);
  return (e - 1.0f) / (e + 1.0f);
}

// write-through coherent stores: visible at coherence point (L3) once vmcnt
// retires -> release needs only a vmcnt drain, no buffer_wbl2.
__device__ __forceinline__ void st_coh16(f16* p, f16 v) {
  unsigned int b = (unsigned int)__builtin_bit_cast(unsigned short, v);
  asm volatile("global_store_short %0, %1, off sc0 sc1" :: "v"(p), "v"(b) : "memory");
}
__device__ __forceinline__ void st_coh32(f16* p, unsigned v) {
  asm volatile("global_store_dword %0, %1, off sc0 sc1" :: "v"(p), "v"(v) : "memory");
}

// Coherent 16B load straight from the coherence point (L3): dual of the
// coherent stores. No acquire fence / buffer_inv anywhere -> read-only data
// (x, staged weights) stays cached. Result NOT ready until s_waitcnt vmcnt.
#define LD_COH(dst, base, OFF)                                             \
  asm volatile("global_load_dwordx4 %0, %1, off offset:" #OFF " sc0 sc1"   \
               : "=v"(dst) : "v"(base))

#define LD16(arr, base)                                    \
  LD_COH(arr[0],  base, 0);   LD_COH(arr[1],  base, 64);   \
  LD_COH(arr[2],  base, 128); LD_COH(arr[3],  base, 192);  \
  LD_COH(arr[4],  base, 256); LD_COH(arr[5],  base, 320);  \
  LD_COH(arr[6],  base, 384); LD_COH(arr[7],  base, 448);  \
  LD_COH(arr[8],  base, 512); LD_COH(arr[9],  base, 576);  \
  LD_COH(arr[10], base, 640); LD_COH(arr[11], base, 704);  \
  LD_COH(arr[12], base, 768); LD_COH(arr[13], base, 832);  \
  LD_COH(arr[14], base, 896); LD_COH(arr[15], base, 960)

// counted wait + scheduler fence (rule #18: sched_barrier stops hipcc from
// hoisting register-only MFMAs above the inline-asm waitcnt)
#define WAIT_VM(N)                                                         \
  do {                                                                     \
    asm volatile("s_waitcnt vmcnt(" #N ")" ::: "memory");                  \
    __builtin_amdgcn_sched_barrier(0);                                     \
  } while (0)

// Lane-parallel poll of per-producer monotonic progress flags (per-WAVE sync
// planes: batch rows are partitioned across waves, so wave v only consumes
// data produced by wave v of peer WGs; no __syncthreads in the step loop).
// "All flags >= t" bounds group skew to <=1 step -> 2-deep h parity buffers
// are WAR-safe. No acquire fence: consumers use sc0/sc1 loads directly.
// Bounded fuel turns any sync bug into a terminating wrong answer.
// Returns the last value this lane observed (for look-ahead checks).
__device__ __forceinline__ unsigned wait_flags(unsigned* fl, unsigned tgt, int& fuel) {
  unsigned v;
  while (true) {
    v = __hip_atomic_load(fl, __ATOMIC_RELAXED, __HIP_MEMORY_SCOPE_AGENT);
    if (__all((int)(v >= tgt))) break;
    if (--fuel < 0) break;             // safety tripwire
    __builtin_amdgcn_s_sleep(1);       // back off: don't hammer the flag lines
  }
  return v;
}

// Release-publish (per wave): drain this wave's coherent stores, then lane 0
// bumps the wave's flag with a relaxed RMW (RMWs execute at the coherence
// point, so pollers on other XCDs observe them). [r9 A/B: plain-store flag
// was not faster; RMW is the proven path]
#define PUBLISH(myf)                                                        \
  do {                                                                      \
    asm volatile("s_waitcnt vmcnt(0)" ::: "memory");                        \
    if (lane == 0)                                                          \
      __hip_atomic_fetch_add((myf), 1u, __ATOMIC_RELAXED,                   \
                             __HIP_MEMORY_SCOPE_AGENT);                     \
  } while (0)

// Fused skewed recurrence, 96 blocks (1 WG/CU; LDS 128 KB dynamic):
//   blocks 0..31 : layer-1, 16 WGs/dir x 32 cols
//   blocks 32..95: layer-2, 32 WGs/dir x 16 cols
// Flags per dir (u32): [0..63] h1 (wg*4+wave), [64..127] c1 (wg*4+wave),
// [128..255] h2 (wg*4+wave). Layer-1 free-runs on its h ring; its h stores
// drain+publish FIRST (critical edge, 4 dense dwords), then c1 stores
// drain+publish in the shadow of peers' detect+load (r8: merging costs
// +2.8 us/step). Layer-2 levers this round:
//   - plC LOOK-AHEAD: after a successful c1 wait, if all c1 flags >= t+8,
//     skip the plC poll for 7 steps (layer-1 has no back-pressure and runs
//     ahead; this removes ~7/8 of the plC L3 round-trips).
//   - y stores moved AFTER publish: dead-end data (read by fc_out post-
//     kernel) no longer sits in the critical pre-publish vmcnt(0) drain.
__global__ __launch_bounds__(256, 1) void lstm_fused(
    const float* __restrict__ w_ih1, const float* __restrict__ w_hh1,
    const float* __restrict__ b_ih1, const float* __restrict__ b_hh1,
    const float* __restrict__ w_ih2, const float* __restrict__ w_hh2,
    const float* __restrict__ b_ih2, const float* __restrict__ b_hh2,
    const float* __restrict__ w_ih3, const float* __restrict__ w_hh3,
    const float* __restrict__ b_ih3, const float* __restrict__ b_hh3,
    const float* __restrict__ w_ih4, const float* __restrict__ w_hh4,
    const float* __restrict__ b_ih4, const float* __restrict__ b_hh4,
    const float* __restrict__ x,
    f16* __restrict__ C1, f16* __restrict__ Y,
    f16* __restrict__ h1buf, f16* __restrict__ h2buf,
    unsigned* __restrict__ grpc, unsigned* __restrict__ rootc)
{
  (void)rootc;
  extern __shared__ f16 wlds[];         // 128 KB dynamic
  const int tid = threadIdx.x;
  const int lane = tid & 63, wave = tid >> 6;
  const int col = lane & 15, quad = lane >> 4;
  const int m0 = wave * 16, b0 = m0 + quad * 4;
  int fuel = 1 << 21;                   // bounded-spin budget per wave

  if (blockIdx.x < 32) {
    // ---------------- layer-1 role: 32 cols, K=512, 8 N-tiles ----------------
    const int dir = blockIdx.x >> 4, wg = blockIdx.x & 15, j0 = wg * 32;
    const float* whh = dir ? w_hh3 : w_hh1;
    const float* wih = dir ? w_ih3 : w_ih1;
    const float* bi  = dir ? b_ih3 : b_ih1;
    const float* bh  = dir ? b_hh3 : b_hh1;
    unsigned* flg  = grpc + dir * 256;
    unsigned* myfH = flg + wg * 4 + wave;            // h1 flag
    unsigned* myfC = flg + 64 + wg * 4 + wave;       // c1 flag
    unsigned* plp  = flg + (lane & 15) * 4 + wave;   // 16 peer h1 flags, my plane

    // stage weights into MFMA B-frag order; tile n: gate g=n&3, half=n>>2.
    // PAIRED col mapping: tile-col r -> global gate col j0 + 2*r + half.
    for (int idx = tid; idx < 8 * 16 * 64; idx += 256) {
      const int n = idx >> 10, kk = (idx >> 6) & 15, L = idx & 63;
      const int r = L & 15, q = L >> 4;
      const int g = n & 3, half = n >> 2;
      const float* src = whh + (size_t)(g * 512 + j0 + 2 * r + half) * HID
                             + kk * 32 + q * 8;
      f16* dst = wlds + idx * 8;
#pragma unroll
      for (int j = 0; j < 8; ++j) dst[j] = (f16)src[j];
    }

    float bias[2][4], wx[2][4];
#pragma unroll
    for (int half = 0; half < 2; ++half)
#pragma unroll
      for (int g = 0; g < 4; ++g) {
        const int row = g * 512 + j0 + 2 * col + half;   // paired mapping
        bias[half][g] = bi[row] + bh[row];
        wx[half][g]   = wih[row];        // w_ih is [4H][1]
      }
    float cst[2][4] = {{0.f,0.f,0.f,0.f},{0.f,0.f,0.f,0.f}};

    f16* C1d = C1 + (size_t)dir * T_LEN * BATCH * HID;
    f16* hb  = h1buf + (size_t)dir * 2 * BATCH * HID;
    __syncthreads();                     // weights staged (only barrier)

    for (int t = 0; t < T_LEN; ++t) {
      if (t > 0) wait_flags(plp, (unsigned)t, fuel);   // peers done step t-1

      const int teff = dir ? (T_LEN - 1 - t) : t;
      const f16* hA = hb + (t & 1) * BATCH * HID;
      f16*       hN = hb + ((t + 1) & 1) * BATCH * HID;
      const f16* aptr = hA + (size_t)(m0 + col) * HID + quad * 8;

      __builtin_amdgcn_sched_barrier(0);   // nothing drifts above the batch
      f16x8 a[16];
      LD16(a, aptr);                       // 16 coherent loads in flight
      // x loads AFTER the h chunks: tail of the vmcnt queue (r9 lesson:
      // ahead of them they delay WAIT_VM(8)); retire under the MFMA phase.
      float xv[4];
#pragma unroll
      for (int r = 0; r < 4; ++r)
        xv[r] = x[(size_t)(b0 + r) * T_LEN + teff];
      __builtin_amdgcn_sched_barrier(0);   // pin x issue here (no sinking)

      f32x4 acc[8];
#pragma unroll
      for (int n = 0; n < 8; ++n) acc[n] = (f32x4){0.f, 0.f, 0.f, 0.f};

      WAIT_VM(8);                          // first 8 h chunks landed
#pragma unroll
      for (int kk = 0; kk < 8; ++kk) {
#pragma unroll
        for (int n = 0; n < 8; ++n) {
          f16x8 b = *(const f16x8*)(wlds + ((n * 16 + kk) * 64 + lane) * 8);
          acc[n] = __builtin_amdgcn_mfma_f32_16x16x32_f16(a[kk], b, acc[n], 0, 0, 0);
        }
      }
      WAIT_VM(0);                          // rest + x landed
#pragma unroll
      for (int kk = 8; kk < 16; ++kk) {
#pragma unroll
        for (int n = 0; n < 8; ++n) {
          f16x8 b = *(const f16x8*)(wlds + ((n * 16 + kk) * 64 + lane) * 8);
          acc[n] = __builtin_amdgcn_mfma_f32_16x16x32_f16(a[kk], b, acc[n], 0, 0, 0);
        }
      }

      unsigned cpk[4], hpk[4];
#pragma unroll
      for (int r = 0; r < 4; ++r) {
        unsigned short cb[2], hb2[2];
#pragma unroll
        for (int half = 0; half < 2; ++half) {
          const float gi = sigm(acc[0 + half * 4][r] + wx[half][0] * xv[r] + bias[half][0]);
          const float gf = sigm(acc[1 + half * 4][r] + wx[half][1] * xv[r] + bias[half][1]);
          const float gg = tanh_f(acc[2 + half * 4][r] + wx[half][2] * xv[r] + bias[half][2]);
          const float go = sigm(acc[3 + half * 4][r] + wx[half][3] * xv[r] + bias[half][3]);
          const float c = gf * cst[half][r] + gi * gg;
          cst[half][r] = c;
          const float h = go * tanh_f(c);
          cb[half]  = __builtin_bit_cast(unsigned short, (f16)c);
          hb2[half] = __builtin_bit_cast(unsigned short, (f16)h);
        }
        cpk[r] = (unsigned)cb[0]  | ((unsigned)cb[1]  << 16);   // cols 2c,2c+1
        hpk[r] = (unsigned)hb2[0] | ((unsigned)hb2[1] << 16);
      }

      // h stores first: the critical intra-layer ring edge (4 dense dwords)
#pragma unroll
      for (int r = 0; r < 4; ++r)
        st_coh32(hN + (size_t)(b0 + r) * HID + j0 + 2 * col, hpk[r]);
      PUBLISH(myfH);                       // h1 flag = t+1

      // c1 stores second: slack edge (hidden under peers' detect+load phase)
      f16* c1row = C1d + (size_t)t * BATCH * HID;
#pragma unroll
      for (int r = 0; r < 4; ++r)
        st_coh32(c1row + (size_t)(b0 + r) * HID + j0 + 2 * col, cpk[r]);
      PUBLISH(myfC);                       // c1 flag = t+1
    }
  } else {
    // ---------------- layer-2 role: 16 cols, K=1024, 4 N-tiles (one/gate) ----
    const int bb = blockIdx.x - 32;
    const int dir = bb >> 5, wg = bb & 31, j0 = wg * 16;
    const float* wih = dir ? w_ih4 : w_ih2;
    const float* whh = dir ? w_hh4 : w_hh2;
    const float* bi  = dir ? b_ih4 : b_ih2;
    const float* bh  = dir ? b_hh4 : b_hh2;
    unsigned* flg  = grpc + dir * 256;
    unsigned* myf  = flg + 128 + wg * 4 + wave;       // h2 flag
    unsigned* plC  = flg + 64 + (lane & 15) * 4 + wave;   // c1 producer flags
    unsigned* plH  = flg + 128 + (lane & 31) * 4 + wave;  // own group flags

    // tile n = gate; K = [c1 (0..511) | h2 (512..1023)]
    for (int idx = tid; idx < 4 * 32 * 64; idx += 256) {
      const int n = idx >> 11, kk = (idx >> 6) & 31, L = idx & 63;
      const int r = L & 15, q = L >> 4;
      const int grow = n * 512 + j0 + r;
      const int k = kk * 32 + q * 8;
      const float* src = (k < 512) ? (wih + (size_t)grow * HID + k)
                                   : (whh + (size_t)grow * HID + (k - 512));
      f16* dst = wlds + idx * 8;
#pragma unroll
      for (int j = 0; j < 8; ++j) dst[j] = (f16)src[j];
    }

    const int jg = j0 + col;
    float bias[4];
#pragma unroll
    for (int g = 0; g < 4; ++g) bias[g] = bi[g * 512 + jg] + bh[g * 512 + jg];
    float cst[4] = {0.f, 0.f, 0.f, 0.f};

    const f16* C1d = C1 + (size_t)dir * T_LEN * BATCH * HID;
    f16* Yd = Y + (size_t)dir * T_LEN * BATCH * HID;
    f16* hb = h2buf + (size_t)dir * 2 * BATCH * HID;
    __syncthreads();                     // weights staged (only barrier)

    int skipC = 0;                       // plC look-ahead credit
    for (int t = 0; t < T_LEN; ++t) {
      // ---- c1 wait: skipped when look-ahead credit shows layer-1 is ahead
      if (skipC > 0) {
        --skipC;
      } else {
        unsigned v = wait_flags(plC, (unsigned)(t + 1), fuel);
        if (__all((int)(v >= (unsigned)(t + 8)))) skipC = 7;
      }

      const f16* c1t = C1d + (size_t)t * BATCH * HID;
      const f16* aptrC = c1t + (size_t)(m0 + col) * HID + quad * 8;
      __builtin_amdgcn_sched_barrier(0);
      f16x8 a[16];
      LD16(a, aptrC);                    // c1 loads in flight...

      // ...their latency hides under the own-group poll round-trip
      if (t > 0) wait_flags(plH, (unsigned)t, fuel);   // peers done step t-1

      const f16* hA = hb + (t & 1) * BATCH * HID;
      f16*       hN = hb + ((t + 1) & 1) * BATCH * HID;
      const f16* aptrH = hA + (size_t)(m0 + col) * HID + quad * 8;
      __builtin_amdgcn_sched_barrier(0);
      f16x8 a2[16];
      LD16(a2, aptrH);                   // h2 loads in flight

      f32x4 acc[4];
#pragma unroll
      for (int n = 0; n < 4; ++n) acc[n] = (f32x4){0.f, 0.f, 0.f, 0.f};

      WAIT_VM(16);                       // c1 chunks done (h2 still flying)
#pragma unroll
      for (int kk = 0; kk < 16; ++kk) {
#pragma unroll
        for (int n = 0; n < 4; ++n) {
          f16x8 b = *(const f16x8*)(wlds + ((n * 32 + kk) * 64 + lane) * 8);
          acc[n] = __builtin_amdgcn_mfma_f32_16x16x32_f16(a[kk], b, acc[n], 0, 0, 0);
        }
      }
      WAIT_VM(0);                        // h2 chunks done
#pragma unroll
      for (int kk = 0; kk < 16; ++kk) {
#pragma unroll
        for (int n = 0; n < 4; ++n) {
          f16x8 b = *(const f16x8*)(wlds + ((n * 32 + 16 + kk) * 64 + lane) * 8);
          acc[n] = __builtin_amdgcn_mfma_f32_16x16x32_f16(a2[kk], b, acc[n], 0, 0, 0);
        }
      }

      f16 yv[4], hv[4];
#pragma unroll
      for (int r = 0; r < 4; ++r) {
        const float gi = sigm(acc[0][r] + bias[0]);
        const float gf = sigm(acc[1][r] + bias[1]);
        const float gg = tanh_f(acc[2][r] + bias[2]);
        const float go = sigm(acc[3][r] + bias[3]);
        const float c = gf * cst[r] + gi * gg;
        cst[r] = c;
        yv[r] = (f16)c;
        hv[r] = (f16)(go * tanh_f(c));
      }
      // h2 stores only in the critical drain
#pragma unroll
      for (int r = 0; r < 4; ++r)
        st_coh16(hN + (size_t)(b0 + r) * HID + jg, hv[r]);
      PUBLISH(myf);                      // h2 flag = t+1

      // y stores after publish: dead-end data, drains under next step
      f16* yrow = Yd + (size_t)t * BATCH * HID;
#pragma unroll
      for (int r = 0; r < 4; ++r)
        yrow[(size_t)(b0 + r) * HID + jg] = yv[r];
    }
  }
}

// ---------- output FC, both directions ----------
__global__ __launch_bounds__(256) void fc_out(
    const f16* __restrict__ Y,
    const float* __restrict__ fw, const float* __restrict__ fb,
    const float* __restrict__ bw, const float* __restrict__ bb,
    float* __restrict__ out)
{
  const int dir = blockIdx.x >> 9;
  const int t = blockIdx.x & 511;
  const int tid = threadIdx.x;
  const int b = tid & 63;
  const int c0 = (tid >> 6) * 16;
  const float* W  = dir ? bw : fw;
  const float* Bv = dir ? bb : fb;
  const f16* yrow = Y + ((size_t)(dir * T_LEN + t) * BATCH + b) * HID;

  float acc[16];
#pragma unroll
  for (int c = 0; c < 16; ++c) acc[c] = 0.f;

  for (int k = 0; k < HID; k += 8) {
    f16x8 yv = *(const f16x8*)(yrow + k);
    float yf[8];
#pragma unroll
    for (int j = 0; j < 8; ++j) yf[j] = (float)yv[j];
#pragma unroll
    for (int c = 0; c < 16; ++c) {
      const float* wr = W + (size_t)(c0 + c) * HID + k;
      const float4 w0 = *(const float4*)wr;
      const float4 w1 = *(const float4*)(wr + 4);
      acc[c] += yf[0] * w0.x + yf[1] * w0.y + yf[2] * w0.z + yf[3] * w0.w
              + yf[4] * w1.x + yf[5] * w1.y + yf[6] * w1.z + yf[7] * w1.w;
    }
  }
  float* orow = out + (size_t)dir * (BATCH * T_LEN * 64)
                    + ((size_t)b * T_LEN + t) * 64 + c0;
#pragma unroll
  for (int c = 0; c < 16; ++c) orow[c] = acc[c] + Bv[c0 + c];
}

// ---------- launch ----------
extern "C" void kernel_launch(void* const* d_in, const int* in_sizes, int n_in,
                              void* d_out, int out_size, void* d_ws, size_t ws_size,
                              hipStream_t stream) {
  const float* x     = (const float*)d_in[0];
  const float* w_ih1 = (const float*)d_in[1];
  const float* w_hh1 = (const float*)d_in[2];
  const float* b_ih1 = (const float*)d_in[3];
  const float* b_hh1 = (const float*)d_in[4];
  const float* w_ih2 = (const float*)d_in[5];
  const float* w_hh2 = (const float*)d_in[6];
  const float* b_ih2 = (const float*)d_in[7];
  const float* b_hh2 = (const float*)d_in[8];
  const float* w_ih3 = (const float*)d_in[9];
  const float* w_hh3 = (const float*)d_in[10];
  const float* b_ih3 = (const float*)d_in[11];
  const float* b_hh3 = (const float*)d_in[12];
  const float* w_ih4 = (const float*)d_in[13];
  const float* w_hh4 = (const float*)d_in[14];
  const float* b_ih4 = (const float*)d_in[15];
  const float* b_hh4 = (const float*)d_in[16];
  const float* fc_w  = (const float*)d_in[17];
  const float* fc_b  = (const float*)d_in[18];
  const float* bfc_w = (const float*)d_in[19];
  const float* bfc_b = (const float*)d_in[20];

  // ws layout (bytes):
  //   [h1 256KB][h2 256KB][flags 2KB][pad][C1 64MB][Y 64MB]
  char* ws = (char*)d_ws;
  f16* h1b = (f16*)(ws);
  f16* h2b = (f16*)(ws + 262144);
  unsigned* grpc  = (unsigned*)(ws + 524288);   // flags [2 dirs][256 u32]
  unsigned* rootc = (unsigned*)(ws + 526336);   // unused (kept for ABI)
  const size_t SEQ_BYTES = (size_t)2 * T_LEN * BATCH * HID * sizeof(f16); // 64 MB
  f16* C1 = (f16*)(ws + 532480);
  f16* Yb = (f16*)(ws + 532480 + SEQ_BYTES);

  // zero h-state buffers + flags (ws is poisoned 0xAA each launch)
  (void)hipMemsetAsync(ws, 0, 526336, stream);

  // raise dynamic-LDS cap to 128 KB (host-side config call, capture-safe)
  static bool lds_set = false;
  if (!lds_set) {
    (void)hipFuncSetAttribute((const void*)lstm_fused,
                              hipFuncAttributeMaxDynamicSharedMemorySize, 131072);
    lds_set = true;
  }

  lstm_fused<<<96, 256, 131072, stream>>>(
      w_ih1, w_hh1, b_ih1, b_hh1, w_ih2, w_hh2, b_ih2, b_hh2,
      w_ih3, w_hh3, b_ih3, b_hh3, w_ih4, w_hh4, b_ih4, b_hh4,
      x, C1, Yb, h1b, h2b, grpc, rootc);
  fc_out<<<1024, 256, 0, stream>>>(Yb, fc_w, fc_b, bfc_w, bfc_b, (float*)d_out);
}

// Round 14
// 4101.414 us; speedup vs baseline: 1.0140x; 1.0140x over previous
//
#include <hip/hip_runtime.h>

typedef _Float16 f16;
typedef f16   f16x8 __attribute__((ext_vector_type(8)));
typedef float f32x4 __attribute__((ext_vector_type(4)));

#define T_LEN 512
#define BATCH 64
#define HID   512

__device__ __forceinline__ float sigm(float x) { return 1.0f / (1.0f + __expf(-x)); }
__device__ __forceinline__ float tanh_f(float x) {
  x = fminf(fmaxf(x, -15.0f), 15.0f);
  float e = __expf(2.0f * x);
  return (e - 1.0f) / (e + 1.0f);
}

// write-through coherent stores: visible at coherence point (L3) once vmcnt
// retires -> release needs only a vmcnt drain, no buffer_wbl2.
__device__ __forceinline__ void st_coh16(f16* p, f16 v) {
  unsigned int b = (unsigned int)__builtin_bit_cast(unsigned short, v);
  asm volatile("global_store_short %0, %1, off sc0 sc1" :: "v"(p), "v"(b) : "memory");
}
__device__ __forceinline__ void st_coh32(f16* p, unsigned v) {
  asm volatile("global_store_dword %0, %1, off sc0 sc1" :: "v"(p), "v"(v) : "memory");
}

// Coherent 16B load straight from the coherence point (L3): dual of the
// coherent stores. No acquire fence / buffer_inv anywhere -> read-only data
// (x, staged weights) stays cached. Result NOT ready until s_waitcnt vmcnt.
#define LD_COH(dst, base, OFF)                                             \
  asm volatile("global_load_dwordx4 %0, %1, off offset:" #OFF " sc0 sc1"   \
               : "=v"(dst) : "v"(base))

#define LD16(arr, base)                                    \
  LD_COH(arr[0],  base, 0);   LD_COH(arr[1],  base, 64);   \
  LD_COH(arr[2],  base, 128); LD_COH(arr[3],  base, 192);  \
  LD_COH(arr[4],  base, 256); LD_COH(arr[5],  base, 320);  \
  LD_COH(arr[6],  base, 384); LD_COH(arr[7],  base, 448);  \
  LD_COH(arr[8],  base, 512); LD_COH(arr[9],  base, 576);  \
  LD_COH(arr[10], base, 640); LD_COH(arr[11], base, 704);  \
  LD_COH(arr[12], base, 768); LD_COH(arr[13], base, 832);  \
  LD_COH(arr[14], base, 896); LD_COH(arr[15], base, 960)

// counted wait + scheduler fence (rule #18: sched_barrier stops hipcc from
// hoisting register-only MFMAs above the inline-asm waitcnt)
#define WAIT_VM(N)                                                         \
  do {                                                                     \
    asm volatile("s_waitcnt vmcnt(" #N ")" ::: "memory");                  \
    __builtin_amdgcn_sched_barrier(0);                                     \
  } while (0)

// Lane-parallel poll of per-producer monotonic progress flags (per-WAVE sync
// planes: batch rows are partitioned across waves, so wave v only consumes
// data produced by wave v of peer WGs; no __syncthreads in the step loop).
// "All flags >= t" bounds group skew to <=1 step -> 2-deep h parity buffers
// are WAR-safe. No acquire fence: consumers use sc0/sc1 loads directly.
// Bounded fuel turns any sync bug into a terminating wrong answer.
__device__ __forceinline__ void wait_flags(unsigned* fl, unsigned tgt, int& fuel) {
  while (true) {
    unsigned v = __hip_atomic_load(fl, __ATOMIC_RELAXED, __HIP_MEMORY_SCOPE_AGENT);
    if (__all((int)(v >= tgt))) break;
    if (--fuel < 0) break;             // safety tripwire
    __builtin_amdgcn_s_sleep(1);       // back off: don't hammer the flag lines
  }
}

// Release-publish (per wave): drain this wave's coherent stores, then lane 0
// bumps the wave's flag with a relaxed RMW (RMWs execute at the coherence
// point, so pollers on other XCDs observe them).
#define PUBLISH(myf)                                                        \
  do {                                                                      \
    asm volatile("s_waitcnt vmcnt(0)" ::: "memory");                        \
    if (lane == 0)                                                          \
      __hip_atomic_fetch_add((myf), 1u, __ATOMIC_RELAXED,                   \
                             __HIP_MEMORY_SCOPE_AGENT);                     \
  } while (0)

// Fused skewed recurrence, 96 blocks (1 WG/CU; LDS 128 KB dynamic):
//   blocks 0..31 : layer-1, 16 WGs/dir x 32 cols
//   blocks 32..95: layer-2, 32 WGs/dir x 16 cols
// Flags per dir (u32): [0..63] h1 (wg*4+wave), [64..127] c1 (wg*4+wave),
// [128..255] h2 (wg*4+wave). Layer-1 free-runs on its h ring; its h stores
// drain+publish FIRST (critical edge, 4 dense dwords only), then c1 stores
// drain+publish in the shadow of peers' detect+load phase (r8 proved merging
// them onto one drain costs +2.8 us/step). Layer-2: c1 loads issued before
// the own-group poll so the poll round-trip hides their latency.
// PAIRED col mapping (layer-1): tile-col r -> global gate col j0 + 2*r +
// half, so each lane's two half-tile results are adjacent columns -> packed
// dword stores (64x32B -> 32x64B dense write-through segments per wave).
__global__ __launch_bounds__(256, 1) void lstm_fused(
    const float* __restrict__ w_ih1, const float* __restrict__ w_hh1,
    const float* __restrict__ b_ih1, const float* __restrict__ b_hh1,
    const float* __restrict__ w_ih2, const float* __restrict__ w_hh2,
    const float* __restrict__ b_ih2, const float* __restrict__ b_hh2,
    const float* __restrict__ w_ih3, const float* __restrict__ w_hh3,
    const float* __restrict__ b_ih3, const float* __restrict__ b_hh3,
    const float* __restrict__ w_ih4, const float* __restrict__ w_hh4,
    const float* __restrict__ b_ih4, const float* __restrict__ b_hh4,
    const float* __restrict__ x,
    f16* __restrict__ C1, f16* __restrict__ Y,
    f16* __restrict__ h1buf, f16* __restrict__ h2buf,
    unsigned* __restrict__ grpc, unsigned* __restrict__ rootc)
{
  (void)rootc;
  extern __shared__ f16 wlds[];         // 128 KB dynamic
  const int tid = threadIdx.x;
  const int lane = tid & 63, wave = tid >> 6;
  const int col = lane & 15, quad = lane >> 4;
  const int m0 = wave * 16, b0 = m0 + quad * 4;
  int fuel = 1 << 21;                   // bounded-spin budget per wave

  if (blockIdx.x < 32) {
    // ---------------- layer-1 role: 32 cols, K=512, 8 N-tiles ----------------
    const int dir = blockIdx.x >> 4, wg = blockIdx.x & 15, j0 = wg * 32;
    const float* whh = dir ? w_hh3 : w_hh1;
    const float* wih = dir ? w_ih3 : w_ih1;
    const float* bi  = dir ? b_ih3 : b_ih1;
    const float* bh  = dir ? b_hh3 : b_hh1;
    unsigned* flg  = grpc + dir * 256;
    unsigned* myfH = flg + wg * 4 + wave;            // h1 flag
    unsigned* myfC = flg + 64 + wg * 4 + wave;       // c1 flag
    unsigned* plp  = flg + (lane & 15) * 4 + wave;   // 16 peer h1 flags, my plane

    // stage weights into MFMA B-frag order; tile n: gate g=n&3, half=n>>2.
    // PAIRED col mapping: tile-col r -> global gate col j0 + 2*r + half.
    for (int idx = tid; idx < 8 * 16 * 64; idx += 256) {
      const int n = idx >> 10, kk = (idx >> 6) & 15, L = idx & 63;
      const int r = L & 15, q = L >> 4;
      const int g = n & 3, half = n >> 2;
      const float* src = whh + (size_t)(g * 512 + j0 + 2 * r + half) * HID
                             + kk * 32 + q * 8;
      f16* dst = wlds + idx * 8;
#pragma unroll
      for (int j = 0; j < 8; ++j) dst[j] = (f16)src[j];
    }

    float bias[2][4], wx[2][4];
#pragma unroll
    for (int half = 0; half < 2; ++half)
#pragma unroll
      for (int g = 0; g < 4; ++g) {
        const int row = g * 512 + j0 + 2 * col + half;   // paired mapping
        bias[half][g] = bi[row] + bh[row];
        wx[half][g]   = wih[row];        // w_ih is [4H][1]
      }
    float cst[2][4] = {{0.f,0.f,0.f,0.f},{0.f,0.f,0.f,0.f}};

    f16* C1d = C1 + (size_t)dir * T_LEN * BATCH * HID;
    f16* hb  = h1buf + (size_t)dir * 2 * BATCH * HID;
    __syncthreads();                     // weights staged (only barrier)

    for (int t = 0; t < T_LEN; ++t) {
      if (t > 0) wait_flags(plp, (unsigned)t, fuel);   // peers done step t-1

      const f16* hA = hb + (t & 1) * BATCH * HID;
      f16*       hN = hb + ((t + 1) & 1) * BATCH * HID;
      const f16* aptr = hA + (size_t)(m0 + col) * HID + quad * 8;

      __builtin_amdgcn_sched_barrier(0);   // nothing drifts above the batch
      f16x8 a[16];
      LD16(a, aptr);                       // 16 coherent loads in flight

      f32x4 acc[8];
#pragma unroll
      for (int n = 0; n < 8; ++n) acc[n] = (f32x4){0.f, 0.f, 0.f, 0.f};

      WAIT_VM(8);                          // first 8 chunks landed
#pragma unroll
      for (int kk = 0; kk < 8; ++kk) {
#pragma unroll
        for (int n = 0; n < 8; ++n) {
          f16x8 b = *(const f16x8*)(wlds + ((n * 16 + kk) * 64 + lane) * 8);
          acc[n] = __builtin_amdgcn_mfma_f32_16x16x32_f16(a[kk], b, acc[n], 0, 0, 0);
        }
      }
      WAIT_VM(0);                          // rest landed
#pragma unroll
      for (int kk = 8; kk < 16; ++kk) {
#pragma unroll
        for (int n = 0; n < 8; ++n) {
          f16x8 b = *(const f16x8*)(wlds + ((n * 16 + kk) * 64 + lane) * 8);
          acc[n] = __builtin_amdgcn_mfma_f32_16x16x32_f16(a[kk], b, acc[n], 0, 0, 0);
        }
      }

      // x loads on the act path (r9/r10 lesson: hoisting them into the vmcnt
      // queue between LD16 and the MFMA waits delays WAIT_VM(8) -> MFMA start)
      const int teff = dir ? (T_LEN - 1 - t) : t;
      unsigned cpk[4], hpk[4];
#pragma unroll
      for (int r = 0; r < 4; ++r) {
        const float xv = x[(size_t)(b0 + r) * T_LEN + teff];   // cached
        unsigned short cb[2], hb2[2];
#pragma unroll
        for (int half = 0; half < 2; ++half) {
          const float gi = sigm(acc[0 + half * 4][r] + wx[half][0] * xv + bias[half][0]);
          const float gf = sigm(acc[1 + half * 4][r] + wx[half][1] * xv + bias[half][1]);
          const float gg = tanh_f(acc[2 + half * 4][r] + wx[half][2] * xv + bias[half][2]);
          const float go = sigm(acc[3 + half * 4][r] + wx[half][3] * xv + bias[half][3]);
          const float c = gf * cst[half][r] + gi * gg;
          cst[half][r] = c;
          const float h = go * tanh_f(c);
          cb[half]  = __builtin_bit_cast(unsigned short, (f16)c);
          hb2[half] = __builtin_bit_cast(unsigned short, (f16)h);
        }
        cpk[r] = (unsigned)cb[0]  | ((unsigned)cb[1]  << 16);   // cols 2c,2c+1
        hpk[r] = (unsigned)hb2[0] | ((unsigned)hb2[1] << 16);
      }

      // h stores first: the critical intra-layer ring edge (4 dense dwords)
#pragma unroll
      for (int r = 0; r < 4; ++r)
        st_coh32(hN + (size_t)(b0 + r) * HID + j0 + 2 * col, hpk[r]);
      PUBLISH(myfH);                       // h1 flag = t+1

      // c1 stores second: slack edge (hidden under peers' detect+load phase)
      f16* c1row = C1d + (size_t)t * BATCH * HID;
#pragma unroll
      for (int r = 0; r < 4; ++r)
        st_coh32(c1row + (size_t)(b0 + r) * HID + j0 + 2 * col, cpk[r]);
      PUBLISH(myfC);                       // c1 flag = t+1
    }
  } else {
    // ---------------- layer-2 role: 16 cols, K=1024, 4 N-tiles (one/gate) ----
    const int bb = blockIdx.x - 32;
    const int dir = bb >> 5, wg = bb & 31, j0 = wg * 16;
    const float* wih = dir ? w_ih4 : w_ih2;
    const float* whh = dir ? w_hh4 : w_hh2;
    const float* bi  = dir ? b_ih4 : b_ih2;
    const float* bh  = dir ? b_hh4 : b_hh2;
    unsigned* flg  = grpc + dir * 256;
    unsigned* myf  = flg + 128 + wg * 4 + wave;       // h2 flag
    unsigned* plC  = flg + 64 + (lane & 15) * 4 + wave;   // c1 producer flags
    unsigned* plH  = flg + 128 + (lane & 31) * 4 + wave;  // own group flags

    // tile n = gate; K = [c1 (0..511) | h2 (512..1023)]
    for (int idx = tid; idx < 4 * 32 * 64; idx += 256) {
      const int n = idx >> 11, kk = (idx >> 6) & 31, L = idx & 63;
      const int r = L & 15, q = L >> 4;
      const int grow = n * 512 + j0 + r;
      const int k = kk * 32 + q * 8;
      const float* src = (k < 512) ? (wih + (size_t)grow * HID + k)
                                   : (whh + (size_t)grow * HID + (k - 512));
      f16* dst = wlds + idx * 8;
#pragma unroll
      for (int j = 0; j < 8; ++j) dst[j] = (f16)src[j];
    }

    const int jg = j0 + col;
    float bias[4];
#pragma unroll
    for (int g = 0; g < 4; ++g) bias[g] = bi[g * 512 + jg] + bh[g * 512 + jg];
    float cst[4] = {0.f, 0.f, 0.f, 0.f};

    const f16* C1d = C1 + (size_t)dir * T_LEN * BATCH * HID;
    f16* Yd = Y + (size_t)dir * T_LEN * BATCH * HID;
    f16* hb = h2buf + (size_t)dir * 2 * BATCH * HID;
    __syncthreads();                     // weights staged (only barrier)

    for (int t = 0; t < T_LEN; ++t) {
      // ---- c1 loads: layer-1 runs ahead, so this wait is usually satisfied
      wait_flags(plC, (unsigned)(t + 1), fuel);    // c1_t published

      const f16* c1t = C1d + (size_t)t * BATCH * HID;
      const f16* aptrC = c1t + (size_t)(m0 + col) * HID + quad * 8;
      __builtin_amdgcn_sched_barrier(0);
      f16x8 a[16];
      LD16(a, aptrC);                    // c1 loads in flight...

      // ...their latency hides under the own-group poll round-trip
      if (t > 0) wait_flags(plH, (unsigned)t, fuel);   // peers done step t-1

      const f16* hA = hb + (t & 1) * BATCH * HID;
      f16*       hN = hb + ((t + 1) & 1) * BATCH * HID;
      const f16* aptrH = hA + (size_t)(m0 + col) * HID + quad * 8;
      __builtin_amdgcn_sched_barrier(0);
      f16x8 a2[16];
      LD16(a2, aptrH);                   // h2 loads in flight

      f32x4 acc[4];
#pragma unroll
      for (int n = 0; n < 4; ++n) acc[n] = (f32x4){0.f, 0.f, 0.f, 0.f};

      WAIT_VM(16);                       // c1 chunks done (h2 still flying)
#pragma unroll
      for (int kk = 0; kk < 16; ++kk) {
#pragma unroll
        for (int n = 0; n < 4; ++n) {
          f16x8 b = *(const f16x8*)(wlds + ((n * 32 + kk) * 64 + lane) * 8);
          acc[n] = __builtin_amdgcn_mfma_f32_16x16x32_f16(a[kk], b, acc[n], 0, 0, 0);
        }
      }
      WAIT_VM(0);                        // h2 chunks done
#pragma unroll
      for (int kk = 0; kk < 16; ++kk) {
#pragma unroll
        for (int n = 0; n < 4; ++n) {
          f16x8 b = *(const f16x8*)(wlds + ((n * 32 + 16 + kk) * 64 + lane) * 8);
          acc[n] = __builtin_amdgcn_mfma_f32_16x16x32_f16(a2[kk], b, acc[n], 0, 0, 0);
        }
      }

      f16* yrow = Yd + (size_t)t * BATCH * HID;
#pragma unroll
      for (int r = 0; r < 4; ++r) {
        const float gi = sigm(acc[0][r] + bias[0]);
        const float gf = sigm(acc[1][r] + bias[1]);
        const float gg = tanh_f(acc[2][r] + bias[2]);
        const float go = sigm(acc[3][r] + bias[3]);
        const float c = gf * cst[r] + gi * gg;
        cst[r] = c;
        const float h = go * tanh_f(c);
        const int b = b0 + r;
        yrow[(size_t)b * HID + jg] = (f16)c;   // plain: consumed post-kernel
        st_coh16(hN + (size_t)b * HID + jg, (f16)h);
      }
      PUBLISH(myf);                      // h2 flag = t+1
    }
  }
}

// ---------- output FC, both directions ----------
__global__ __launch_bounds__(256) void fc_out(
    const f16* __restrict__ Y,
    const float* __restrict__ fw, const float* __restrict__ fb,
    const float* __restrict__ bw, const float* __restrict__ bb,
    float* __restrict__ out)
{
  const int dir = blockIdx.x >> 9;
  const int t = blockIdx.x & 511;
  const int tid = threadIdx.x;
  const int b = tid & 63;
  const int c0 = (tid >> 6) * 16;
  const float* W  = dir ? bw : fw;
  const float* Bv = dir ? bb : fb;
  const f16* yrow = Y + ((size_t)(dir * T_LEN + t) * BATCH + b) * HID;

  float acc[16];
#pragma unroll
  for (int c = 0; c < 16; ++c) acc[c] = 0.f;

  for (int k = 0; k < HID; k += 8) {
    f16x8 yv = *(const f16x8*)(yrow + k);
    float yf[8];
#pragma unroll
    for (int j = 0; j < 8; ++j) yf[j] = (float)yv[j];
#pragma unroll
    for (int c = 0; c < 16; ++c) {
      const float* wr = W + (size_t)(c0 + c) * HID + k;
      const float4 w0 = *(const float4*)wr;
      const float4 w1 = *(const float4*)(wr + 4);
      acc[c] += yf[0] * w0.x + yf[1] * w0.y + yf[2] * w0.z + yf[3] * w0.w
              + yf[4] * w1.x + yf[5] * w1.y + yf[6] * w1.z + yf[7] * w1.w;
    }
  }
  float* orow = out + (size_t)dir * (BATCH * T_LEN * 64)
                    + ((size_t)b * T_LEN + t) * 64 + c0;
#pragma unroll
  for (int c = 0; c < 16; ++c) orow[c] = acc[c] + Bv[c0 + c];
}

// ---------- launch ----------
extern "C" void kernel_launch(void* const* d_in, const int* in_sizes, int n_in,
                              void* d_out, int out_size, void* d_ws, size_t ws_size,
                              hipStream_t stream) {
  const float* x     = (const float*)d_in[0];
  const float* w_ih1 = (const float*)d_in[1];
  const float* w_hh1 = (const float*)d_in[2];
  const float* b_ih1 = (const float*)d_in[3];
  const float* b_hh1 = (const float*)d_in[4];
  const float* w_ih2 = (const float*)d_in[5];
  const float* w_hh2 = (const float*)d_in[6];
  const float* b_ih2 = (const float*)d_in[7];
  const float* b_hh2 = (const float*)d_in[8];
  const float* w_ih3 = (const float*)d_in[9];
  const float* w_hh3 = (const float*)d_in[10];
  const float* b_ih3 = (const float*)d_in[11];
  const float* b_hh3 = (const float*)d_in[12];
  const float* w_ih4 = (const float*)d_in[13];
  const float* w_hh4 = (const float*)d_in[14];
  const float* b_ih4 = (const float*)d_in[15];
  const float* b_hh4 = (const float*)d_in[16];
  const float* fc_w  = (const float*)d_in[17];
  const float* fc_b  = (const float*)d_in[18];
  const float* bfc_w = (const float*)d_in[19];
  const float* bfc_b = (const float*)d_in[20];

  // ws layout (bytes):
  //   [h1 256KB][h2 256KB][flags 2KB][pad][C1 64MB][Y 64MB]
  char* ws = (char*)d_ws;
  f16* h1b = (f16*)(ws);
  f16* h2b = (f16*)(ws + 262144);
  unsigned* grpc  = (unsigned*)(ws + 524288);   // flags [2 dirs][256 u32]
  unsigned* rootc = (unsigned*)(ws + 526336);   // unused (kept for ABI)
  const size_t SEQ_BYTES = (size_t)2 * T_LEN * BATCH * HID * sizeof(f16); // 64 MB
  f16* C1 = (f16*)(ws + 532480);
  f16* Yb = (f16*)(ws + 532480 + SEQ_BYTES);

  // zero h-state buffers + flags (ws is poisoned 0xAA each launch)
  (void)hipMemsetAsync(ws, 0, 526336, stream);

  // raise dynamic-LDS cap to 128 KB (host-side config call, capture-safe)
  static bool lds_set = false;
  if (!lds_set) {
    (void)hipFuncSetAttribute((const void*)lstm_fused,
                              hipFuncAttributeMaxDynamicSharedMemorySize, 131072);
    lds_set = true;
  }

  lstm_fused<<<96, 256, 131072, stream>>>(
      w_ih1, w_hh1, b_ih1, b_hh1, w_ih2, w_hh2, b_ih2, b_hh2,
      w_ih3, w_hh3, b_ih3, b_hh3, w_ih4, w_hh4, b_ih4, b_hh4,
      x, C1, Yb, h1b, h2b, grpc, rootc);
  fc_out<<<1024, 256, 0, stream>>>(Yb, fc_w, fc_b, bfc_w, bfc_b, (float*)d_out);
}

// Round 15
// 3691.621 us; speedup vs baseline: 1.1265x; 1.1110x over previous
//
#include <hip/hip_runtime.h>

typedef _Float16 f16;
typedef f16   f16x8 __attribute__((ext_vector_type(8)));
typedef float f32x4 __attribute__((ext_vector_type(4)));

#define T_LEN 512
#define BATCH 64
#define HID   512

__device__ __forceinline__ float sigm(float x) { return 1.0f / (1.0f + __expf(-x)); }
__device__ __forceinline__ float tanh_f(float x) {
  x = fminf(fmaxf(x, -15.0f), 15.0f);
  float e = __expf(2.0f * x);
  return (e - 1.0f) / (e + 1.0f);
}

// write-through coherent stores: visible at coherence point (L3) once vmcnt
// retires -> release needs only a vmcnt drain, no buffer_wbl2.
__device__ __forceinline__ void st_coh16(f16* p, f16 v) {
  unsigned int b = (unsigned int)__builtin_bit_cast(unsigned short, v);
  asm volatile("global_store_short %0, %1, off sc0 sc1" :: "v"(p), "v"(b) : "memory");
}
__device__ __forceinline__ void st_coh32(f16* p, unsigned v) {
  asm volatile("global_store_dword %0, %1, off sc0 sc1" :: "v"(p), "v"(v) : "memory");
}

// Coherent 16B load straight from the coherence point (L3): dual of the
// coherent stores. No acquire fence / buffer_inv anywhere -> read-only data
// (x, staged weights) stays cached. Result NOT ready until s_waitcnt vmcnt.
#define LD_COH(dst, base, OFF)                                             \
  asm volatile("global_load_dwordx4 %0, %1, off offset:" #OFF " sc0 sc1"   \
               : "=v"(dst) : "v"(base))

#define LD16(arr, base)                                    \
  LD_COH(arr[0],  base, 0);   LD_COH(arr[1],  base, 64);   \
  LD_COH(arr[2],  base, 128); LD_COH(arr[3],  base, 192);  \
  LD_COH(arr[4],  base, 256); LD_COH(arr[5],  base, 320);  \
  LD_COH(arr[6],  base, 384); LD_COH(arr[7],  base, 448);  \
  LD_COH(arr[8],  base, 512); LD_COH(arr[9],  base, 576);  \
  LD_COH(arr[10], base, 640); LD_COH(arr[11], base, 704);  \
  LD_COH(arr[12], base, 768); LD_COH(arr[13], base, 832);  \
  LD_COH(arr[14], base, 896); LD_COH(arr[15], base, 960)

// counted wait + scheduler fence (rule #18: sched_barrier stops hipcc from
// hoisting register-only MFMAs above the inline-asm waitcnt)
#define WAIT_VM(N)                                                         \
  do {                                                                     \
    asm volatile("s_waitcnt vmcnt(" #N ")" ::: "memory");                  \
    __builtin_amdgcn_sched_barrier(0);                                     \
  } while (0)

// Lane-parallel poll of per-producer monotonic progress flags (per-WAVE sync
// planes: batch rows are partitioned across waves, so wave v only consumes
// data produced by wave v of peer WGs; no __syncthreads in the step loop).
// "All flags >= t" bounds group skew to <=1 step -> 2-deep h parity buffers
// are WAR-safe. No acquire fence: consumers use sc0/sc1 loads directly.
// Bounded fuel turns any sync bug into a terminating wrong answer.
__device__ __forceinline__ void wait_flags(unsigned* fl, unsigned tgt, int& fuel) {
  while (true) {
    unsigned v = __hip_atomic_load(fl, __ATOMIC_RELAXED, __HIP_MEMORY_SCOPE_AGENT);
    if (__all((int)(v >= tgt))) break;
    if (--fuel < 0) break;             // safety tripwire
    __builtin_amdgcn_s_sleep(1);       // back off: don't hammer the flag lines
  }
}

// Release-publish (per wave): drain this wave's coherent stores, then lane 0
// bumps the wave's flag with a relaxed RMW (RMWs execute at the coherence
// point, so pollers on other XCDs observe them).
#define PUBLISH(myf)                                                        \
  do {                                                                      \
    asm volatile("s_waitcnt vmcnt(0)" ::: "memory");                        \
    if (lane == 0)                                                          \
      __hip_atomic_fetch_add((myf), 1u, __ATOMIC_RELAXED,                   \
                             __HIP_MEMORY_SCOPE_AGENT);                     \
  } while (0)

// Fused skewed recurrence, 96 blocks (1 WG/CU; LDS 128 KB dynamic):
//   blocks 0..31 : layer-1, 16 WGs/dir x 32 cols
//   blocks 32..95: layer-2, 32 WGs/dir x 16 cols
// Flags per dir (u32): [0..63] h1 (wg*4+wave), [64..127] c1 (wg*4+wave),
// [128..255] h2 (wg*4+wave). Layer-1 free-runs on its h ring; its h stores
// drain+publish FIRST (critical edge, 4 dense dwords only), then c1 stores
// drain+publish in the shadow of peers' detect+load phase (r8 proved merging
// them onto one drain costs +2.8 us/step). Layer-2: c1 loads issued before
// the own-group poll so the poll round-trip hides their latency.
// PAIRED col mapping (layer-1): tile-col r -> global gate col j0 + 2*r +
// half, so each lane's two half-tile results are adjacent columns -> packed
// dword stores (64x32B -> 32x64B dense write-through segments per wave).
// [This kernel is byte-identical to the r7/r14 verified version.]
__global__ __launch_bounds__(256, 1) void lstm_fused(
    const float* __restrict__ w_ih1, const float* __restrict__ w_hh1,
    const float* __restrict__ b_ih1, const float* __restrict__ b_hh1,
    const float* __restrict__ w_ih2, const float* __restrict__ w_hh2,
    const float* __restrict__ b_ih2, const float* __restrict__ b_hh2,
    const float* __restrict__ w_ih3, const float* __restrict__ w_hh3,
    const float* __restrict__ b_ih3, const float* __restrict__ b_hh3,
    const float* __restrict__ w_ih4, const float* __restrict__ w_hh4,
    const float* __restrict__ b_ih4, const float* __restrict__ b_hh4,
    const float* __restrict__ x,
    f16* __restrict__ C1, f16* __restrict__ Y,
    f16* __restrict__ h1buf, f16* __restrict__ h2buf,
    unsigned* __restrict__ grpc, unsigned* __restrict__ rootc)
{
  (void)rootc;
  extern __shared__ f16 wlds[];         // 128 KB dynamic
  const int tid = threadIdx.x;
  const int lane = tid & 63, wave = tid >> 6;
  const int col = lane & 15, quad = lane >> 4;
  const int m0 = wave * 16, b0 = m0 + quad * 4;
  int fuel = 1 << 21;                   // bounded-spin budget per wave

  if (blockIdx.x < 32) {
    // ---------------- layer-1 role: 32 cols, K=512, 8 N-tiles ----------------
    const int dir = blockIdx.x >> 4, wg = blockIdx.x & 15, j0 = wg * 32;
    const float* whh = dir ? w_hh3 : w_hh1;
    const float* wih = dir ? w_ih3 : w_ih1;
    const float* bi  = dir ? b_ih3 : b_ih1;
    const float* bh  = dir ? b_hh3 : b_hh1;
    unsigned* flg  = grpc + dir * 256;
    unsigned* myfH = flg + wg * 4 + wave;            // h1 flag
    unsigned* myfC = flg + 64 + wg * 4 + wave;       // c1 flag
    unsigned* plp  = flg + (lane & 15) * 4 + wave;   // 16 peer h1 flags, my plane

    // stage weights into MFMA B-frag order; tile n: gate g=n&3, half=n>>2.
    // PAIRED col mapping: tile-col r -> global gate col j0 + 2*r + half.
    for (int idx = tid; idx < 8 * 16 * 64; idx += 256) {
      const int n = idx >> 10, kk = (idx >> 6) & 15, L = idx & 63;
      const int r = L & 15, q = L >> 4;
      const int g = n & 3, half = n >> 2;
      const float* src = whh + (size_t)(g * 512 + j0 + 2 * r + half) * HID
                             + kk * 32 + q * 8;
      f16* dst = wlds + idx * 8;
#pragma unroll
      for (int j = 0; j < 8; ++j) dst[j] = (f16)src[j];
    }

    float bias[2][4], wx[2][4];
#pragma unroll
    for (int half = 0; half < 2; ++half)
#pragma unroll
      for (int g = 0; g < 4; ++g) {
        const int row = g * 512 + j0 + 2 * col + half;   // paired mapping
        bias[half][g] = bi[row] + bh[row];
        wx[half][g]   = wih[row];        // w_ih is [4H][1]
      }
    float cst[2][4] = {{0.f,0.f,0.f,0.f},{0.f,0.f,0.f,0.f}};

    f16* C1d = C1 + (size_t)dir * T_LEN * BATCH * HID;
    f16* hb  = h1buf + (size_t)dir * 2 * BATCH * HID;
    __syncthreads();                     // weights staged (only barrier)

    for (int t = 0; t < T_LEN; ++t) {
      if (t > 0) wait_flags(plp, (unsigned)t, fuel);   // peers done step t-1

      const f16* hA = hb + (t & 1) * BATCH * HID;
      f16*       hN = hb + ((t + 1) & 1) * BATCH * HID;
      const f16* aptr = hA + (size_t)(m0 + col) * HID + quad * 8;

      __builtin_amdgcn_sched_barrier(0);   // nothing drifts above the batch
      f16x8 a[16];
      LD16(a, aptr);                       // 16 coherent loads in flight

      f32x4 acc[8];
#pragma unroll
      for (int n = 0; n < 8; ++n) acc[n] = (f32x4){0.f, 0.f, 0.f, 0.f};

      WAIT_VM(8);                          // first 8 chunks landed
#pragma unroll
      for (int kk = 0; kk < 8; ++kk) {
#pragma unroll
        for (int n = 0; n < 8; ++n) {
          f16x8 b = *(const f16x8*)(wlds + ((n * 16 + kk) * 64 + lane) * 8);
          acc[n] = __builtin_amdgcn_mfma_f32_16x16x32_f16(a[kk], b, acc[n], 0, 0, 0);
        }
      }
      WAIT_VM(0);                          // rest landed
#pragma unroll
      for (int kk = 8; kk < 16; ++kk) {
#pragma unroll
        for (int n = 0; n < 8; ++n) {
          f16x8 b = *(const f16x8*)(wlds + ((n * 16 + kk) * 64 + lane) * 8);
          acc[n] = __builtin_amdgcn_mfma_f32_16x16x32_f16(a[kk], b, acc[n], 0, 0, 0);
        }
      }

      // x loads on the act path (r9/r10 lesson: hoisting them into the vmcnt
      // queue between LD16 and the MFMA waits delays WAIT_VM(8) -> MFMA start)
      const int teff = dir ? (T_LEN - 1 - t) : t;
      unsigned cpk[4], hpk[4];
#pragma unroll
      for (int r = 0; r < 4; ++r) {
        const float xv = x[(size_t)(b0 + r) * T_LEN + teff];   // cached
        unsigned short cb[2], hb2[2];
#pragma unroll
        for (int half = 0; half < 2; ++half) {
          const float gi = sigm(acc[0 + half * 4][r] + wx[half][0] * xv + bias[half][0]);
          const float gf = sigm(acc[1 + half * 4][r] + wx[half][1] * xv + bias[half][1]);
          const float gg = tanh_f(acc[2 + half * 4][r] + wx[half][2] * xv + bias[half][2]);
          const float go = sigm(acc[3 + half * 4][r] + wx[half][3] * xv + bias[half][3]);
          const float c = gf * cst[half][r] + gi * gg;
          cst[half][r] = c;
          const float h = go * tanh_f(c);
          cb[half]  = __builtin_bit_cast(unsigned short, (f16)c);
          hb2[half] = __builtin_bit_cast(unsigned short, (f16)h);
        }
        cpk[r] = (unsigned)cb[0]  | ((unsigned)cb[1]  << 16);   // cols 2c,2c+1
        hpk[r] = (unsigned)hb2[0] | ((unsigned)hb2[1] << 16);
      }

      // h stores first: the critical intra-layer ring edge (4 dense dwords)
#pragma unroll
      for (int r = 0; r < 4; ++r)
        st_coh32(hN + (size_t)(b0 + r) * HID + j0 + 2 * col, hpk[r]);
      PUBLISH(myfH);                       // h1 flag = t+1

      // c1 stores second: slack edge (hidden under peers' detect+load phase)
      f16* c1row = C1d + (size_t)t * BATCH * HID;
#pragma unroll
      for (int r = 0; r < 4; ++r)
        st_coh32(c1row + (size_t)(b0 + r) * HID + j0 + 2 * col, cpk[r]);
      PUBLISH(myfC);                       // c1 flag = t+1
    }
  } else {
    // ---------------- layer-2 role: 16 cols, K=1024, 4 N-tiles (one/gate) ----
    const int bb = blockIdx.x - 32;
    const int dir = bb >> 5, wg = bb & 31, j0 = wg * 16;
    const float* wih = dir ? w_ih4 : w_ih2;
    const float* whh = dir ? w_hh4 : w_hh2;
    const float* bi  = dir ? b_ih4 : b_ih2;
    const float* bh  = dir ? b_hh4 : b_hh2;
    unsigned* flg  = grpc + dir * 256;
    unsigned* myf  = flg + 128 + wg * 4 + wave;       // h2 flag
    unsigned* plC  = flg + 64 + (lane & 15) * 4 + wave;   // c1 producer flags
    unsigned* plH  = flg + 128 + (lane & 31) * 4 + wave;  // own group flags

    // tile n = gate; K = [c1 (0..511) | h2 (512..1023)]
    for (int idx = tid; idx < 4 * 32 * 64; idx += 256) {
      const int n = idx >> 11, kk = (idx >> 6) & 31, L = idx & 63;
      const int r = L & 15, q = L >> 4;
      const int grow = n * 512 + j0 + r;
      const int k = kk * 32 + q * 8;
      const float* src = (k < 512) ? (wih + (size_t)grow * HID + k)
                                   : (whh + (size_t)grow * HID + (k - 512));
      f16* dst = wlds + idx * 8;
#pragma unroll
      for (int j = 0; j < 8; ++j) dst[j] = (f16)src[j];
    }

    const int jg = j0 + col;
    float bias[4];
#pragma unroll
    for (int g = 0; g < 4; ++g) bias[g] = bi[g * 512 + jg] + bh[g * 512 + jg];
    float cst[4] = {0.f, 0.f, 0.f, 0.f};

    const f16* C1d = C1 + (size_t)dir * T_LEN * BATCH * HID;
    f16* Yd = Y + (size_t)dir * T_LEN * BATCH * HID;
    f16* hb = h2buf + (size_t)dir * 2 * BATCH * HID;
    __syncthreads();                     // weights staged (only barrier)

    for (int t = 0; t < T_LEN; ++t) {
      // ---- c1 loads: layer-1 runs ahead, so this wait is usually satisfied
      wait_flags(plC, (unsigned)(t + 1), fuel);    // c1_t published

      const f16* c1t = C1d + (size_t)t * BATCH * HID;
      const f16* aptrC = c1t + (size_t)(m0 + col) * HID + quad * 8;
      __builtin_amdgcn_sched_barrier(0);
      f16x8 a[16];
      LD16(a, aptrC);                    // c1 loads in flight...

      // ...their latency hides under the own-group poll round-trip
      if (t > 0) wait_flags(plH, (unsigned)t, fuel);   // peers done step t-1

      const f16* hA = hb + (t & 1) * BATCH * HID;
      f16*       hN = hb + ((t + 1) & 1) * BATCH * HID;
      const f16* aptrH = hA + (size_t)(m0 + col) * HID + quad * 8;
      __builtin_amdgcn_sched_barrier(0);
      f16x8 a2[16];
      LD16(a2, aptrH);                   // h2 loads in flight

      f32x4 acc[4];
#pragma unroll
      for (int n = 0; n < 4; ++n) acc[n] = (f32x4){0.f, 0.f, 0.f, 0.f};

      WAIT_VM(16);                       // c1 chunks done (h2 still flying)
#pragma unroll
      for (int kk = 0; kk < 16; ++kk) {
#pragma unroll
        for (int n = 0; n < 4; ++n) {
          f16x8 b = *(const f16x8*)(wlds + ((n * 32 + kk) * 64 + lane) * 8);
          acc[n] = __builtin_amdgcn_mfma_f32_16x16x32_f16(a[kk], b, acc[n], 0, 0, 0);
        }
      }
      WAIT_VM(0);                        // h2 chunks done
#pragma unroll
      for (int kk = 0; kk < 16; ++kk) {
#pragma unroll
        for (int n = 0; n < 4; ++n) {
          f16x8 b = *(const f16x8*)(wlds + ((n * 32 + 16 + kk) * 64 + lane) * 8);
          acc[n] = __builtin_amdgcn_mfma_f32_16x16x32_f16(a2[kk], b, acc[n], 0, 0, 0);
        }
      }

      f16* yrow = Yd + (size_t)t * BATCH * HID;
#pragma unroll
      for (int r = 0; r < 4; ++r) {
        const float gi = sigm(acc[0][r] + bias[0]);
        const float gf = sigm(acc[1][r] + bias[1]);
        const float gg = tanh_f(acc[2][r] + bias[2]);
        const float go = sigm(acc[3][r] + bias[3]);
        const float c = gf * cst[r] + gi * gg;
        cst[r] = c;
        const float h = go * tanh_f(c);
        const int b = b0 + r;
        yrow[(size_t)b * HID + jg] = (f16)c;   // plain: consumed post-kernel
        st_coh16(hN + (size_t)b * HID + jg, (f16)h);
      }
      PUBLISH(myf);                      // h2 flag = t+1
    }
  }
}

// ---------- fc weight hi/lo split: w = f16(w) + f16(w - f16(w)) ----------
// Makes the MFMA fc path effectively f32-accurate (residual carries the
// low mantissa bits; total representation error ~2^-22 relative).
__global__ __launch_bounds__(256) void conv_w(
    const float* __restrict__ fw, const float* __restrict__ bw,
    f16* __restrict__ whi, f16* __restrict__ wlo)
{
  const int i = blockIdx.x * 256 + threadIdx.x;    // 0..32767
  const float w0 = fw[i];
  const f16 h0 = (f16)w0;
  whi[i] = h0;
  wlo[i] = (f16)(w0 - (float)h0);
  const float w1 = bw[i];
  const f16 h1 = (f16)w1;
  whi[32768 + i] = h1;
  wlo[32768 + i] = (f16)(w1 - (float)h1);
}

// ---------- output FC via MFMA (hi/lo split weights) ----------
// 1024 blocks = (dir, t); 4 waves; wave w covers batch rows 16w..16w+15,
// all 64 classes (4 c-tiles). Fragment layout identical to the verified
// lstm usage: A row = lane&15 (y row m0+col), B col = lane&15 (class),
// D row = quad*4 + reg. acc accumulates BOTH hi and lo MFMA chains.
__global__ __launch_bounds__(256) void fc_mfma(
    const f16* __restrict__ Y,
    const f16* __restrict__ whi, const f16* __restrict__ wlo,
    const float* __restrict__ fb, const float* __restrict__ bb,
    float* __restrict__ out)
{
  const int dir = blockIdx.x >> 9;
  const int t = blockIdx.x & 511;
  const int tid = threadIdx.x;
  const int lane = tid & 63;
  const int col = lane & 15, quad = lane >> 4;
  const int m0 = (tid >> 6) * 16;

  const f16* yt = Y + (size_t)(dir * T_LEN + t) * BATCH * HID;
  const f16* aptr = yt + (size_t)(m0 + col) * HID + quad * 8;
  f16x8 a[16];
#pragma unroll
  for (int kk = 0; kk < 16; ++kk) a[kk] = *(const f16x8*)(aptr + kk * 32);

  const f16* wh = whi + (size_t)dir * 64 * HID;
  const f16* wl = wlo + (size_t)dir * 64 * HID;
  f32x4 acc[4];
#pragma unroll
  for (int n = 0; n < 4; ++n) acc[n] = (f32x4){0.f, 0.f, 0.f, 0.f};

#pragma unroll
  for (int kk = 0; kk < 16; ++kk) {
#pragma unroll
    for (int n = 0; n < 4; ++n) {
      const size_t wo = (size_t)(n * 16 + col) * HID + quad * 8 + kk * 32;
      f16x8 bh = *(const f16x8*)(wh + wo);
      f16x8 bl = *(const f16x8*)(wl + wo);
      acc[n] = __builtin_amdgcn_mfma_f32_16x16x32_f16(a[kk], bh, acc[n], 0, 0, 0);
      acc[n] = __builtin_amdgcn_mfma_f32_16x16x32_f16(a[kk], bl, acc[n], 0, 0, 0);
    }
  }

  const float* Bv = dir ? bb : fb;
  float* obase = out + (size_t)dir * (BATCH * T_LEN * 64);
#pragma unroll
  for (int n = 0; n < 4; ++n) {
    const int c = n * 16 + col;
    const float bv = Bv[c];
#pragma unroll
    for (int r = 0; r < 4; ++r) {
      const int b = m0 + quad * 4 + r;
      obase[((size_t)b * T_LEN + t) * 64 + c] = acc[n][r] + bv;
    }
  }
}

// ---------- fallback output FC (r7-proven scalar path) ----------
__global__ __launch_bounds__(256) void fc_out(
    const f16* __restrict__ Y,
    const float* __restrict__ fw, const float* __restrict__ fb,
    const float* __restrict__ bw, const float* __restrict__ bb,
    float* __restrict__ out)
{
  const int dir = blockIdx.x >> 9;
  const int t = blockIdx.x & 511;
  const int tid = threadIdx.x;
  const int b = tid & 63;
  const int c0 = (tid >> 6) * 16;
  const float* W  = dir ? bw : fw;
  const float* Bv = dir ? bb : fb;
  const f16* yrow = Y + ((size_t)(dir * T_LEN + t) * BATCH + b) * HID;

  float acc[16];
#pragma unroll
  for (int c = 0; c < 16; ++c) acc[c] = 0.f;

  for (int k = 0; k < HID; k += 8) {
    f16x8 yv = *(const f16x8*)(yrow + k);
    float yf[8];
#pragma unroll
    for (int j = 0; j < 8; ++j) yf[j] = (float)yv[j];
#pragma unroll
    for (int c = 0; c < 16; ++c) {
      const float* wr = W + (size_t)(c0 + c) * HID + k;
      const float4 w0 = *(const float4*)wr;
      const float4 w1 = *(const float4*)(wr + 4);
      acc[c] += yf[0] * w0.x + yf[1] * w0.y + yf[2] * w0.z + yf[3] * w0.w
              + yf[4] * w1.x + yf[5] * w1.y + yf[6] * w1.z + yf[7] * w1.w;
    }
  }
  float* orow = out + (size_t)dir * (BATCH * T_LEN * 64)
                    + ((size_t)b * T_LEN + t) * 64 + c0;
#pragma unroll
  for (int c = 0; c < 16; ++c) orow[c] = acc[c] + Bv[c0 + c];
}

// ---------- launch ----------
extern "C" void kernel_launch(void* const* d_in, const int* in_sizes, int n_in,
                              void* d_out, int out_size, void* d_ws, size_t ws_size,
                              hipStream_t stream) {
  const float* x     = (const float*)d_in[0];
  const float* w_ih1 = (const float*)d_in[1];
  const float* w_hh1 = (const float*)d_in[2];
  const float* b_ih1 = (const float*)d_in[3];
  const float* b_hh1 = (const float*)d_in[4];
  const float* w_ih2 = (const float*)d_in[5];
  const float* w_hh2 = (const float*)d_in[6];
  const float* b_ih2 = (const float*)d_in[7];
  const float* b_hh2 = (const float*)d_in[8];
  const float* w_ih3 = (const float*)d_in[9];
  const float* w_hh3 = (const float*)d_in[10];
  const float* b_ih3 = (const float*)d_in[11];
  const float* b_hh3 = (const float*)d_in[12];
  const float* w_ih4 = (const float*)d_in[13];
  const float* w_hh4 = (const float*)d_in[14];
  const float* b_ih4 = (const float*)d_in[15];
  const float* b_hh4 = (const float*)d_in[16];
  const float* fc_w  = (const float*)d_in[17];
  const float* fc_b  = (const float*)d_in[18];
  const float* bfc_w = (const float*)d_in[19];
  const float* bfc_b = (const float*)d_in[20];

  // ws layout (bytes):
  //   [h1 256KB][h2 256KB][flags 2KB][pad][C1 64MB][Y 64MB][whi 128KB][wlo 128KB]
  char* ws = (char*)d_ws;
  f16* h1b = (f16*)(ws);
  f16* h2b = (f16*)(ws + 262144);
  unsigned* grpc  = (unsigned*)(ws + 524288);   // flags [2 dirs][256 u32]
  unsigned* rootc = (unsigned*)(ws + 526336);   // unused (kept for ABI)
  const size_t SEQ_BYTES = (size_t)2 * T_LEN * BATCH * HID * sizeof(f16); // 64 MB
  f16* C1 = (f16*)(ws + 532480);
  f16* Yb = (f16*)(ws + 532480 + SEQ_BYTES);
  const size_t W_OFF = 532480 + 2 * SEQ_BYTES;
  f16* whi = (f16*)(ws + W_OFF);
  f16* wlo = (f16*)(ws + W_OFF + 131072);
  const bool use_mfma_fc = (ws_size >= W_OFF + 262144);

  // zero h-state buffers + flags (ws is poisoned 0xAA each launch)
  (void)hipMemsetAsync(ws, 0, 526336, stream);

  // raise dynamic-LDS cap to 128 KB (host-side config call, capture-safe)
  static bool lds_set = false;
  if (!lds_set) {
    (void)hipFuncSetAttribute((const void*)lstm_fused,
                              hipFuncAttributeMaxDynamicSharedMemorySize, 131072);
    lds_set = true;
  }

  if (use_mfma_fc)
    conv_w<<<128, 256, 0, stream>>>(fc_w, bfc_w, whi, wlo);
  lstm_fused<<<96, 256, 131072, stream>>>(
      w_ih1, w_hh1, b_ih1, b_hh1, w_ih2, w_hh2, b_ih2, b_hh2,
      w_ih3, w_hh3, b_ih3, b_hh3, w_ih4, w_hh4, b_ih4, b_hh4,
      x, C1, Yb, h1b, h2b, grpc, rootc);
  if (use_mfma_fc)
    fc_mfma<<<1024, 256, 0, stream>>>(Yb, whi, wlo, fc_b, bfc_b, (float*)d_out);
  else
    fc_out<<<1024, 256, 0, stream>>>(Yb, fc_w, fc_b, bfc_w, bfc_b, (float*)d_out);
}